// Round 1
// baseline (172.421 us; speedup 1.0000x reference)
//
#include <hip/hip_runtime.h>
#include <math.h>

// Problem constants (fixed by setup_inputs): C=64 channels, HW=128*128, bins=256.
#define C_CH 64
#define HW   16384
#define BINS 256
#define NTHR 256

// ws layout (floats):
//   [0, C_CH*BINS)                 per-channel inclusive cdf of histc(match*mask)
//   [C_CH*BINS, +BINS)             T lookup table (built from channel 0 only)
//   [C_CH*BINS+BINS, +C_CH)        per-channel SSE partial sums

// Kernel A: per-channel min/max of mm = match*mask, then 256-bin LDS histogram,
// then serial inclusive scan -> cdf (float, exact integers).
__global__ __launch_bounds__(NTHR) void kA_hist(const float* __restrict__ match,
                                                const float* __restrict__ mask,
                                                float* __restrict__ cdf) {
    const int c = blockIdx.x;
    const int tid = threadIdx.x;
    const float* m = match + c * HW;

    __shared__ float red[NTHR];

    float mn = INFINITY, mx = -INFINITY;
    for (int i = tid; i < HW; i += NTHR) {
        float v = m[i] * mask[i];
        mn = fminf(mn, v);
        mx = fmaxf(mx, v);
    }
    red[tid] = mn; __syncthreads();
    for (int s = 128; s > 0; s >>= 1) { if (tid < s) red[tid] = fminf(red[tid], red[tid + s]); __syncthreads(); }
    mn = red[0]; __syncthreads();
    red[tid] = mx; __syncthreads();
    for (int s = 128; s > 0; s >>= 1) { if (tid < s) red[tid] = fmaxf(red[tid], red[tid + s]); __syncthreads(); }
    mx = red[0]; __syncthreads();

    // torch.histc semantics: w = (mx-mn)/bins; safe_w = w>0 ? w : 1
    float w = (mx - mn) * (1.0f / 256.0f);   // /256 is exact (power of 2)
    float sw = (w > 0.0f) ? w : 1.0f;

    __shared__ int hist[BINS];
    hist[tid] = 0;
    __syncthreads();

    for (int i = tid; i < HW; i += NTHR) {
        float v = m[i] * mask[i];
        float b = floorf((v - mn) / sw);
        b = fminf(fmaxf(b, 0.0f), 255.0f);   // clip in float like the reference, then cast
        atomicAdd(&hist[(int)b], 1);
    }
    __syncthreads();

    if (tid == 0) {
        int s = 0;
        for (int b = 0; b < BINS; b++) { s += hist[b]; hist[b] = s; }
    }
    __syncthreads();
    cdf[c * BINS + tid] = (float)hist[tid];  // integers <= 16384: exact in fp32
}

// Kernel B: build T[j] (j=0..255) from channel 0 only.
// T[j] = xmin0 + (ratio + idx0)*step0, idx0 = count(cdf0 < j+1),
// ratio = clip((j+1 - cdfprev0[idx0]) / (1e-8 + cdf0[idx0]), 0, 1).
__global__ __launch_bounds__(NTHR) void kB_lut(const float* __restrict__ input,
                                               const float* __restrict__ mask,
                                               const float* __restrict__ cdf,
                                               float* __restrict__ T) {
    const int tid = threadIdx.x;
    __shared__ float red[NTHR];
    __shared__ float c0[BINS];
    c0[tid] = cdf[tid];   // channel 0 cdf

    float mn = INFINITY, mx = -INFINITY;
    for (int i = tid; i < HW; i += NTHR) {
        float v = input[i] * mask[i];   // x = input*mask, channel 0
        mn = fminf(mn, v);
        mx = fmaxf(mx, v);
    }
    red[tid] = mn; __syncthreads();
    for (int s = 128; s > 0; s >>= 1) { if (tid < s) red[tid] = fminf(red[tid], red[tid + s]); __syncthreads(); }
    mn = red[0]; __syncthreads();
    red[tid] = mx; __syncthreads();
    for (int s = 128; s > 0; s >>= 1) { if (tid < s) red[tid] = fmaxf(red[tid], red[tid + s]); __syncthreads(); }
    mx = red[0]; __syncthreads();

    float step = (mx - mn) * (1.0f / 256.0f);
    float rank = (float)(tid + 1);
    int idx = 0;
    for (int b = 0; b < BINS; b++) idx += (c0[b] < rank) ? 1 : 0;   // idx <= 255 (c0[255]=N>=rank)
    float cp = (idx > 0) ? c0[idx - 1] : 0.0f;
    float cc = c0[idx];
    float ratio = (rank - cp) / (1e-8f + cc);
    ratio = fminf(fmaxf(ratio, 0.0f), 1.0f);
    T[tid] = mn + (ratio + (float)idx) * step;
}

// Kernel C: per channel, per element n: corr = T[lower_bound(cdf_c, n+1)],
// accumulate (corr - input*mask)^2 -> partial[c].
__global__ __launch_bounds__(NTHR) void kC_loss(const float* __restrict__ input,
                                                const float* __restrict__ mask,
                                                const float* __restrict__ cdf,
                                                const float* __restrict__ T,
                                                float* __restrict__ partial) {
    const int c = blockIdx.x;
    const int tid = threadIdx.x;
    __shared__ float scdf[BINS];
    __shared__ float sT[BINS];
    scdf[tid] = cdf[c * BINS + tid];
    sT[tid] = T[tid];
    __syncthreads();

    const float* x = input + c * HW;
    float acc = 0.0f;
    for (int n = tid; n < HW; n += NTHR) {
        float rank = (float)(n + 1);
        int lo = 0, hi = BINS;
        while (lo < hi) {                 // lower_bound == count(cdf < rank); exact int fp32 compares
            int mid = (lo + hi) >> 1;
            if (scdf[mid] < rank) lo = mid + 1; else hi = mid;
        }
        lo = (lo > 255) ? 255 : lo;       // defensive; cannot trigger since scdf[255] = N
        float corr = sT[lo];
        float xv = x[n] * mask[n];
        float d = corr - xv;
        acc += d * d;
    }

    __shared__ float red[NTHR];
    red[tid] = acc; __syncthreads();
    for (int s = 128; s > 0; s >>= 1) { if (tid < s) red[tid] += red[tid + s]; __syncthreads(); }
    if (tid == 0) partial[c] = red[0];
}

// Kernel D: mask_sum, sum partials, final scale:
// loss = (sse/(C*N)) * mask_sum * C / (C*N)
__global__ __launch_bounds__(NTHR) void kD_final(const float* __restrict__ mask,
                                                 const float* __restrict__ partial,
                                                 float* __restrict__ out) {
    const int tid = threadIdx.x;
    __shared__ float red[NTHR];

    float s = 0.0f;
    for (int i = tid; i < HW; i += NTHR) s += mask[i];   // 0/1 values: exact
    red[tid] = s; __syncthreads();
    for (int st = 128; st > 0; st >>= 1) { if (tid < st) red[tid] += red[tid + st]; __syncthreads(); }
    float mask_sum = red[0];
    __syncthreads();

    float p = (tid < C_CH) ? partial[tid] : 0.0f;
    red[tid] = p; __syncthreads();
    for (int st = 128; st > 0; st >>= 1) { if (tid < st) red[tid] += red[tid + st]; __syncthreads(); }

    if (tid == 0) {
        double sse  = (double)red[0];
        double mean = sse / (double)(C_CH * HW);
        double loss = mean * (double)mask_sum * (double)C_CH / (double)(C_CH * HW);
        out[0] = (float)loss;
    }
}

extern "C" void kernel_launch(void* const* d_in, const int* in_sizes, int n_in,
                              void* d_out, int out_size, void* d_ws, size_t ws_size,
                              hipStream_t stream) {
    const float* input = (const float*)d_in[0];
    const float* match = (const float*)d_in[1];
    const float* mask  = (const float*)d_in[2];
    // d_in[3] = bins (256) — fixed by the problem, baked into kernel constants.

    float* ws      = (float*)d_ws;
    float* cdf     = ws;                      // C_CH*BINS floats
    float* T       = cdf + C_CH * BINS;       // BINS floats
    float* partial = T + BINS;                // C_CH floats
    float* out     = (float*)d_out;

    kA_hist<<<C_CH, NTHR, 0, stream>>>(match, mask, cdf);
    kB_lut <<<1,    NTHR, 0, stream>>>(input, mask, cdf, T);
    kC_loss<<<C_CH, NTHR, 0, stream>>>(input, mask, cdf, T, partial);
    kD_final<<<1,   NTHR, 0, stream>>>(mask, partial, out);
}

// Round 2
// 96.664 us; speedup vs baseline: 1.7837x; 1.7837x over previous
//
#include <hip/hip_runtime.h>
#include <math.h>

// Problem constants (fixed by setup_inputs): C=64 channels, HW=128*128, bins=256.
#define C_CH   64
#define HW     16384
#define BINS   256
#define SPLIT  8                 // blocks per channel in K1/K3
#define SEG    (HW / SPLIT)      // 2048 elements per block segment
#define NTHR   256

// ---- ws layout (32-bit cells) ----
// [0,65)    enc_min: 64 channels of mm, +1 for x0          (memset 0xFF)
// [65,130)  enc_max: same                                   (memset 0x00)
// [130]     sse accumulator (float)                         (0)
// [131]     mask_sum accumulator (float)                    (0)
// [192, 192+64*256)  cdf (float, per-channel inclusive)
// [192+64*256, +256) T lookup table
#define WS_ENC_MIN 0
#define WS_ENC_MAX 65
#define WS_SSE     130
#define WS_MASKSUM 131
#define WS_CDF     192
#define WS_T       (WS_CDF + C_CH * BINS)

__device__ inline unsigned int encf(float f) {
    unsigned int u = __float_as_uint(f);
    return (u & 0x80000000u) ? ~u : (u | 0x80000000u);
}
__device__ inline float decf(unsigned int e) {
    unsigned int u = (e & 0x80000000u) ? (e ^ 0x80000000u) : ~e;
    return __uint_as_float(u);
}

// K1: per-channel min/max of mm=match*mask (encoded atomics); channel-0 blocks also
// do x0=input*mask min/max and mask partial sums. 512 blocks x 256 threads.
__global__ __launch_bounds__(NTHR) void k1_minmax(const float* __restrict__ input,
                                                  const float* __restrict__ match,
                                                  const float* __restrict__ mask,
                                                  unsigned int* __restrict__ ws) {
    const int c   = blockIdx.x >> 3;        // channel
    const int s   = blockIdx.x & (SPLIT - 1);
    const int tid = threadIdx.x;
    const int base = s * SEG;

    const float* m = match + c * HW + base;
    const float* mk = mask + base;

    float mn = INFINITY, mx = -INFINITY;
    #pragma unroll
    for (int k = 0; k < SEG / NTHR; k++) {
        float v = m[tid + k * NTHR] * mk[tid + k * NTHR];
        mn = fminf(mn, v);
        mx = fmaxf(mx, v);
    }

    __shared__ float red[NTHR];
    red[tid] = mn; __syncthreads();
    for (int st = 128; st > 0; st >>= 1) { if (tid < st) red[tid] = fminf(red[tid], red[tid + st]); __syncthreads(); }
    if (tid == 0) atomicMin(&ws[WS_ENC_MIN + c], encf(red[0]));
    __syncthreads();
    red[tid] = mx; __syncthreads();
    for (int st = 128; st > 0; st >>= 1) { if (tid < st) red[tid] = fmaxf(red[tid], red[tid + st]); __syncthreads(); }
    if (tid == 0) atomicMax(&ws[WS_ENC_MAX + c], encf(red[0]));

    if (c == 0) {
        const float* x = input + base;   // channel 0 of input
        float xmn = INFINITY, xmx = -INFINITY, msum = 0.0f;
        #pragma unroll
        for (int k = 0; k < SEG / NTHR; k++) {
            float mv = mk[tid + k * NTHR];
            float v = x[tid + k * NTHR] * mv;
            xmn = fminf(xmn, v);
            xmx = fmaxf(xmx, v);
            msum += mv;
        }
        __syncthreads();
        red[tid] = xmn; __syncthreads();
        for (int st = 128; st > 0; st >>= 1) { if (tid < st) red[tid] = fminf(red[tid], red[tid + st]); __syncthreads(); }
        if (tid == 0) atomicMin(&ws[WS_ENC_MIN + C_CH], encf(red[0]));
        __syncthreads();
        red[tid] = xmx; __syncthreads();
        for (int st = 128; st > 0; st >>= 1) { if (tid < st) red[tid] = fmaxf(red[tid], red[tid + st]); __syncthreads(); }
        if (tid == 0) atomicMax(&ws[WS_ENC_MAX + C_CH], encf(red[0]));
        __syncthreads();
        red[tid] = msum; __syncthreads();
        for (int st = 128; st > 0; st >>= 1) { if (tid < st) red[tid] += red[tid + st]; __syncthreads(); }
        if (tid == 0) atomicAdd((float*)&ws[WS_MASKSUM], red[0]);
    }
}

// K2: per-channel 256-bin histogram of mm + inclusive scan -> cdf.
// Block for c==0 also builds the T LUT (from channel-0 x min/max + cdf0).
// 64 blocks x 1024 threads (16 waves/CU on the 64 used CUs).
__global__ __launch_bounds__(1024) void k2_hist(const float* __restrict__ match,
                                                const float* __restrict__ mask,
                                                unsigned int* __restrict__ ws) {
    const int c   = blockIdx.x;
    const int tid = threadIdx.x;
    const float* m = match + c * HW;
    float* wsf = (float*)ws;

    const float mn = decf(ws[WS_ENC_MIN + c]);
    const float mx = decf(ws[WS_ENC_MAX + c]);
    float w  = (mx - mn) * (1.0f / 256.0f);     // /256 exact
    float sw = (w > 0.0f) ? w : 1.0f;

    __shared__ int hist[BINS];
    if (tid < BINS) hist[tid] = 0;
    __syncthreads();

    #pragma unroll
    for (int k = 0; k < HW / 1024; k++) {
        int i = tid + k * 1024;
        float v = m[i] * mask[i];
        float b = floorf((v - mn) / sw);
        b = fminf(fmaxf(b, 0.0f), 255.0f);      // clip in float like the reference
        atomicAdd(&hist[(int)b], 1);
    }
    __syncthreads();

    // Hillis-Steele inclusive scan over 256 bins (threads 0..255 participate)
    for (int off = 1; off < BINS; off <<= 1) {
        int v = 0;
        if (tid < BINS) v = hist[tid] + ((tid >= off) ? hist[tid - off] : 0);
        __syncthreads();
        if (tid < BINS) hist[tid] = v;
        __syncthreads();
    }

    if (tid < BINS) wsf[WS_CDF + c * BINS + tid] = (float)hist[tid];  // ints <= 16384: exact

    if (c == 0 && tid < BINS) {
        const float xmn = decf(ws[WS_ENC_MIN + C_CH]);
        const float xmx = decf(ws[WS_ENC_MAX + C_CH]);
        float step = (xmx - xmn) * (1.0f / 256.0f);
        float rank = (float)(tid + 1);
        int idx = 0;
        #pragma unroll 8
        for (int b = 0; b < BINS; b++) idx += (hist[b] < (tid + 1)) ? 1 : 0;  // idx <= 255
        float cp = (idx > 0) ? (float)hist[idx - 1] : 0.0f;
        float cc = (float)hist[idx];
        float ratio = (rank - cp) / (1e-8f + cc);
        ratio = fminf(fmaxf(ratio, 0.0f), 1.0f);
        wsf[WS_T + tid] = xmn + (ratio + (float)idx) * step;
    }
}

// K3: loss. 512 blocks x 256 threads (8/channel). Binary search once per thread,
// then marching pointer (rank and cdf both monotone).
__global__ __launch_bounds__(NTHR) void k3_loss(const float* __restrict__ input,
                                                const float* __restrict__ mask,
                                                unsigned int* __restrict__ ws) {
    const int c   = blockIdx.x >> 3;
    const int s   = blockIdx.x & (SPLIT - 1);
    const int tid = threadIdx.x;
    const int base = s * SEG;
    const float* wsf = (const float*)ws;

    __shared__ float scdf[BINS];
    __shared__ float sT[BINS];
    if (tid < BINS) {
        scdf[tid] = wsf[WS_CDF + c * BINS + tid];
        sT[tid]   = wsf[WS_T + tid];
    }
    __syncthreads();

    const float* x  = input + c * HW + base;
    const float* mk = mask + base;

    // first element: binary search (lower_bound of rank0 = count(cdf < rank0))
    int n0 = base + tid;
    float rank0 = (float)(n0 + 1);
    int lo = 0, hi = BINS;
    while (lo < hi) {
        int mid = (lo + hi) >> 1;
        if (scdf[mid] < rank0) lo = mid + 1; else hi = mid;
    }

    float acc = 0.0f;
    #pragma unroll
    for (int k = 0; k < SEG / NTHR; k++) {
        int i = tid + k * NTHR;
        float rank = (float)(base + i + 1);
        while (scdf[lo] < rank) lo++;          // monotone march; scdf[255]=N bounds it
        float corr = sT[lo];
        float xv = x[i] * mk[i];
        float d = corr - xv;
        acc += d * d;
    }

    __shared__ float red[NTHR];
    red[tid] = acc; __syncthreads();
    for (int st = 128; st > 0; st >>= 1) { if (tid < st) red[tid] += red[tid + st]; __syncthreads(); }
    if (tid == 0) atomicAdd((float*)&ws[WS_SSE], red[0]);
}

// K4: final scale. loss = (sse/(C*N)) * mask_sum * C / (C*N)
__global__ void k4_final(const unsigned int* __restrict__ ws, float* __restrict__ out) {
    if (threadIdx.x == 0) {
        const float* wsf = (const float*)ws;
        double sse = (double)wsf[WS_SSE];
        double msum = (double)wsf[WS_MASKSUM];
        double mean = sse / (double)(C_CH * HW);
        out[0] = (float)(mean * msum * (double)C_CH / (double)(C_CH * HW));
    }
}

extern "C" void kernel_launch(void* const* d_in, const int* in_sizes, int n_in,
                              void* d_out, int out_size, void* d_ws, size_t ws_size,
                              hipStream_t stream) {
    const float* input = (const float*)d_in[0];
    const float* match = (const float*)d_in[1];
    const float* mask  = (const float*)d_in[2];
    unsigned int* ws   = (unsigned int*)d_ws;
    float* out         = (float*)d_out;

    // init: enc_min cells = 0xFFFFFFFF, enc_max/sse/mask_sum = 0
    hipMemsetAsync(ws + WS_ENC_MIN, 0xFF, 65 * sizeof(unsigned int), stream);
    hipMemsetAsync(ws + WS_ENC_MAX, 0x00, (132 - WS_ENC_MAX) * sizeof(unsigned int), stream);

    k1_minmax<<<C_CH * SPLIT, NTHR, 0, stream>>>(input, match, mask, ws);
    k2_hist  <<<C_CH, 1024, 0, stream>>>(match, mask, ws);
    k3_loss  <<<C_CH * SPLIT, NTHR, 0, stream>>>(input, mask, ws);
    k4_final <<<1, 64, 0, stream>>>(ws, out);
}